// Round 2
// baseline (5327.872 us; speedup 1.0000x reference)
//
#include <hip/hip_runtime.h>
#include <cstdint>
#include <cstddef>

// NCA weight generator: x = bilinear_resize(seed, 1024x1024); 64x fused NCA steps; project.
// State layout: CHW planes, fp32, double-buffered in d_ws.
// PRNG: jax threefry2x32, partitionable variant (JAX >= 0.4.30 default):
//   subkey[i] = tf2x32(key=(0,42), x=(0,i))                (raw pair, no XOR)
//   bits[p]   = o0 ^ o1 of tf2x32(subkey, (0,p))           (32-bit random_bits XORs both words)
//   mask      = ((bits >> 9) > (1<<22))                    (uniform(p) > 0.5)

#define HH 1024
#define WW 1024
#define SD 8
#define HID 32
#define TX 32
#define TY 8

__host__ __device__ inline uint32_t rotl32(uint32_t x, int n) {
  return (x << n) | (x >> (32 - n));
}

__host__ __device__ inline void tf2x32(uint32_t k0, uint32_t k1,
                                       uint32_t x0, uint32_t x1,
                                       uint32_t& o0, uint32_t& o1) {
  uint32_t ks0 = k0, ks1 = k1, ks2 = k0 ^ k1 ^ 0x1BD11BDAu;
  x0 += ks0; x1 += ks1;
#define TFR(r) { x0 += x1; x1 = rotl32(x1, (r)); x1 ^= x0; }
  TFR(13) TFR(15) TFR(26) TFR(6)  x0 += ks1; x1 += ks2 + 1u;
  TFR(17) TFR(29) TFR(16) TFR(24) x0 += ks2; x1 += ks0 + 2u;
  TFR(13) TFR(15) TFR(26) TFR(6)  x0 += ks0; x1 += ks1 + 3u;
  TFR(17) TFR(29) TFR(16) TFR(24) x0 += ks1; x1 += ks2 + 4u;
  TFR(13) TFR(15) TFR(26) TFR(6)  x0 += ks2; x1 += ks0 + 5u;
#undef TFR
  o0 = x0; o1 = x1;
}

// ---- bilinear upsample 8x8 -> 1024x1024 (half-pixel, edge-clamped == jax.image.resize) ----
__global__ void init_kernel(const float* __restrict__ seed, float* __restrict__ dst) {
  int p = blockIdx.x * blockDim.x + threadIdx.x;
  if (p >= HH * WW) return;
  int y = p >> 10, x = p & 1023;
  float fy = (y + 0.5f) * (8.0f / HH) - 0.5f;
  float fx = (x + 0.5f) * (8.0f / WW) - 0.5f;
  int y0 = (int)floorf(fy); float wy = fy - (float)y0;
  int x0 = (int)floorf(fx); float wx = fx - (float)x0;
  int y0c = min(max(y0, 0), 7), y1c = min(max(y0 + 1, 0), 7);
  int x0c = min(max(x0, 0), 7), x1c = min(max(x0 + 1, 0), 7);
#pragma unroll
  for (int c = 0; c < SD; ++c) {
    const float* s = seed + c * 64;
    float v00 = s[y0c * 8 + x0c], v01 = s[y0c * 8 + x1c];
    float v10 = s[y1c * 8 + x0c], v11 = s[y1c * 8 + x1c];
    float v0 = v00 + (v01 - v00) * wx;
    float v1 = v10 + (v11 - v10) * wx;
    dst[c * (HH * WW) + p] = v0 + (v1 - v0) * wy;
  }
}

// ---- transpose W1[o][c][ky][kx] -> W1t[(c*9+k)*32 + o] for contiguous scalar loads ----
__global__ void prep_kernel(const float* __restrict__ W1, float* __restrict__ W1t) {
  int i = blockIdx.x * blockDim.x + threadIdx.x;
  if (i < HID * SD * 9) {
    int o = i / 72, r = i % 72;
    W1t[r * HID + o] = W1[i];
  }
}

// ---- fused NCA step: conv3x3 + gelu + conv1x1 + threefry mask + update ----
__global__ __launch_bounds__(256) void step_kernel(
    const float* __restrict__ src, float* __restrict__ dst,
    const float* __restrict__ W1t, const float* __restrict__ b1,
    const float* __restrict__ W2, const float* __restrict__ b2,
    uint32_t key0, uint32_t key1) {
  __shared__ float tile[SD][TY + 2][TX + 2];
  const int tid = threadIdx.x;
  const int gx0 = blockIdx.x * TX - 1;
  const int gy0 = blockIdx.y * TY - 1;

  // stage x-tile + halo (zero pad = SAME conv padding)
  for (int i = tid; i < SD * (TY + 2) * (TX + 2); i += 256) {
    int c = i / ((TY + 2) * (TX + 2));
    int r = i % ((TY + 2) * (TX + 2));
    int ly = r / (TX + 2), lx = r % (TX + 2);
    int gy = gy0 + ly, gx = gx0 + lx;
    float v = 0.0f;
    if ((unsigned)gy < HH && (unsigned)gx < WW)
      v = src[c * (HH * WW) + gy * WW + gx];
    tile[c][ly][lx] = v;
  }
  __syncthreads();

  const int tx = tid & (TX - 1), ty = tid >> 5;

  float h[HID];
#pragma unroll
  for (int o = 0; o < HID; ++o) h[o] = b1[o];

  for (int c = 0; c < SD; ++c) {
#pragma unroll
    for (int ky = 0; ky < 3; ++ky) {
#pragma unroll
      for (int kx = 0; kx < 3; ++kx) {
        float v = tile[c][ty + ky][tx + kx];
        const float* wp = W1t + (c * 9 + ky * 3 + kx) * HID;  // wave-uniform -> s_load
#pragma unroll
        for (int o = 0; o < HID; ++o) h[o] = fmaf(v, wp[o], h[o]);
      }
    }
  }

  // exact gelu: x * 0.5 * (1 + erf(x/sqrt(2)))
#pragma unroll
  for (int o = 0; o < HID; ++o) {
    float v = h[o];
    h[o] = 0.5f * v * (1.0f + erff(v * 0.70710678118654752440f));
  }

  float dx[SD];
#pragma unroll
  for (int o = 0; o < SD; ++o) {
    float acc = b2[o];
    const float* wp = W2 + o * HID;  // contiguous, wave-uniform -> s_load
#pragma unroll
    for (int oc = 0; oc < HID; ++oc) acc = fmaf(h[oc], wp[oc], acc);
    dx[o] = acc * 0.1f;
  }

  const int y = blockIdx.y * TY + ty;
  const int x = blockIdx.x * TX + tx;
  uint32_t r0, r1;
  tf2x32(key0, key1, 0u, (uint32_t)(y * WW + x), r0, r1);
  const uint32_t bits = r0 ^ r1;  // partitionable random_bits: XOR both output words
  const bool m = ((bits >> 9) > 0x400000u);

#pragma unroll
  for (int c = 0; c < SD; ++c) {
    float xv = tile[c][ty + 1][tx + 1];
    dst[c * (HH * WW) + y * WW + x] = m ? (xv + dx[c]) : xv;
  }
}

// ---- final projection: out[p] = bp + sum_c Wp[c] * x[c][p] ----
__global__ void proj_kernel(const float* __restrict__ x,
                            const float* __restrict__ Wp,
                            const float* __restrict__ bp,
                            float* __restrict__ out) {
  int p = blockIdx.x * blockDim.x + threadIdx.x;
  if (p >= HH * WW) return;
  float acc = bp[0];
#pragma unroll
  for (int c = 0; c < SD; ++c) acc = fmaf(x[c * (HH * WW) + p], Wp[c], acc);
  out[p] = acc;
}

extern "C" void kernel_launch(void* const* d_in, const int* in_sizes, int n_in,
                              void* d_out, int out_size, void* d_ws, size_t ws_size,
                              hipStream_t stream) {
  (void)in_sizes; (void)n_in; (void)out_size; (void)ws_size;
  const float* seed = (const float*)d_in[0];
  const float* W1   = (const float*)d_in[1];
  const float* b1   = (const float*)d_in[2];
  const float* W2   = (const float*)d_in[3];
  const float* b2   = (const float*)d_in[4];
  const float* Wp   = (const float*)d_in[5];
  const float* bp   = (const float*)d_in[6];
  float* out  = (float*)d_out;
  float* buf0 = (float*)d_ws;
  float* buf1 = buf0 + (size_t)SD * HH * WW;
  float* W1t  = buf1 + (size_t)SD * HH * WW;

  // 64 subkeys of jax.random.split(jax.random.key(42), 64), partitionable/foldlike:
  // subkey[i] = raw output pair of tf2x32((0,42), (0,i)) — NO xor for split.
  uint32_t ka[64], kb[64];
  for (int i = 0; i < 64; ++i) tf2x32(0u, 42u, 0u, (uint32_t)i, ka[i], kb[i]);

  hipLaunchKernelGGL(prep_kernel, dim3(9), dim3(256), 0, stream, W1, W1t);
  hipLaunchKernelGGL(init_kernel, dim3((HH * WW) / 256), dim3(256), 0, stream, seed, buf0);

  dim3 grid(WW / TX, HH / TY);
  float* s = buf0; float* d = buf1;
  for (int i = 0; i < 64; ++i) {
    hipLaunchKernelGGL(step_kernel, grid, dim3(256), 0, stream,
                       s, d, W1t, b1, W2, b2, ka[i], kb[i]);
    float* t = s; s = d; d = t;
  }
  hipLaunchKernelGGL(proj_kernel, dim3((HH * WW) / 256), dim3(256), 0, stream,
                     s, Wp, bp, out);
}

// Round 3
// 1921.271 us; speedup vs baseline: 2.7731x; 2.7731x over previous
//
#include <hip/hip_runtime.h>
#include <cstdint>
#include <cstddef>

// NCA: x = bilinear(seed)->1024x1024 NHWC fp32; 64x [conv3x3(8->32)+gelu, conv1x1(32->8)*0.1,
// masked add]; project 8->1. Convs via mfma_f32_16x16x32_f16 implicit GEMM.
// K-order k = tap*8 + c so an A-fragment (8 k-consecutive) = one tap's 8 channels = ds_read_b128.
// PRNG: jax threefry2x32 partitionable: subkey[i]=raw pair tf2x32((0,42),(0,i));
// bits[p]=o0^o1 of tf2x32(subkey,(0,p)); mask = (bits>>9) > 2^22.

#define HH 1024
#define WW 1024
#define SD 8
#define HID 32
#define TX 32
#define TY 16

typedef _Float16 f16x8 __attribute__((ext_vector_type(8)));
typedef float f32x4 __attribute__((ext_vector_type(4)));

__host__ __device__ inline uint32_t rotl32(uint32_t x, int n) {
  return (x << n) | (x >> (32 - n));
}

__host__ __device__ inline void tf2x32(uint32_t k0, uint32_t k1,
                                       uint32_t x0, uint32_t x1,
                                       uint32_t& o0, uint32_t& o1) {
  uint32_t ks0 = k0, ks1 = k1, ks2 = k0 ^ k1 ^ 0x1BD11BDAu;
  x0 += ks0; x1 += ks1;
#define TFR(r) { x0 += x1; x1 = rotl32(x1, (r)); x1 ^= x0; }
  TFR(13) TFR(15) TFR(26) TFR(6)  x0 += ks1; x1 += ks2 + 1u;
  TFR(17) TFR(29) TFR(16) TFR(24) x0 += ks2; x1 += ks0 + 2u;
  TFR(13) TFR(15) TFR(26) TFR(6)  x0 += ks0; x1 += ks1 + 3u;
  TFR(17) TFR(29) TFR(16) TFR(24) x0 += ks1; x1 += ks2 + 4u;
  TFR(13) TFR(15) TFR(26) TFR(6)  x0 += ks2; x1 += ks0 + 5u;
#undef TFR
  o0 = x0; o1 = x1;
}

// ---- bilinear upsample 8x8 -> 1024x1024, NHWC fp32 out ----
__global__ void init_kernel(const float* __restrict__ seed, float* __restrict__ dst) {
  int p = blockIdx.x * blockDim.x + threadIdx.x;
  if (p >= HH * WW) return;
  int y = p >> 10, x = p & 1023;
  float fy = (y + 0.5f) * (8.0f / HH) - 0.5f;
  float fx = (x + 0.5f) * (8.0f / WW) - 0.5f;
  int y0 = (int)floorf(fy); float wy = fy - (float)y0;
  int x0 = (int)floorf(fx); float wx = fx - (float)x0;
  int y0c = min(max(y0, 0), 7), y1c = min(max(y0 + 1, 0), 7);
  int x0c = min(max(x0, 0), 7), x1c = min(max(x0 + 1, 0), 7);
  float vals[8];
#pragma unroll
  for (int c = 0; c < SD; ++c) {
    const float* s = seed + c * 64;
    float v00 = s[y0c * 8 + x0c], v01 = s[y0c * 8 + x1c];
    float v10 = s[y1c * 8 + x0c], v11 = s[y1c * 8 + x1c];
    float v0 = v00 + (v01 - v00) * wx;
    float v1 = v10 + (v11 - v10) * wx;
    vals[c] = v0 + (v1 - v0) * wy;
  }
  f32x4 lo = {vals[0], vals[1], vals[2], vals[3]};
  f32x4 hi = {vals[4], vals[5], vals[6], vals[7]};
  *(f32x4*)(dst + (size_t)p * 8) = lo;
  *(f32x4*)(dst + (size_t)p * 8 + 4) = hi;
}

// ---- pack W1/W2 into MFMA B-fragment order ----
// W1f[nt][kc][lane][j]: n = nt*16+(lane&15), k = kc*32+(lane>>4)*8+j; k=tap*8+c
//   -> tap = kc*4+(lane>>4), c = j; val = tap<9 ? W1[n][c][tap] : 0
// W2f[lane][j]: n = lane&15, k = (lane>>4)*8+j; val = n<8 ? W2[n][k] : 0
__global__ void prep_kernel(const float* __restrict__ W1, const float* __restrict__ W2,
                            _Float16* __restrict__ w1f, _Float16* __restrict__ w2f) {
  int tid = threadIdx.x;
  for (int i = tid; i < 2 * 3 * 64; i += 256) {
    int nt = i / 192, rem = i % 192;
    int kc = rem / 64, lane = rem % 64;
    int n = nt * 16 + (lane & 15);
    int tap = kc * 4 + (lane >> 4);
#pragma unroll
    for (int j = 0; j < 8; ++j) {
      float v = (tap < 9) ? W1[(n * SD + j) * 9 + tap] : 0.0f;
      w1f[i * 8 + j] = (_Float16)v;
    }
  }
  if (tid < 64) {
    int n = tid & 15;
#pragma unroll
    for (int j = 0; j < 8; ++j) {
      int k = (tid >> 4) * 8 + j;
      float v = (n < 8) ? W2[n * HID + k] : 0.0f;
      w2f[tid * 8 + j] = (_Float16)v;
    }
  }
}

// ---- fused NCA step, MFMA implicit GEMM ----
__global__ __launch_bounds__(256) void step_kernel(
    const float* __restrict__ src, float* __restrict__ dst,
    const _Float16* __restrict__ w1f, const _Float16* __restrict__ w2f,
    const float* __restrict__ b1, const float* __restrict__ b2,
    uint32_t key0, uint32_t key1) {
  __shared__ _Float16 tile[(TY + 2) * (TX + 2) * SD];   // NHWC f16, halo +1
  __shared__ _Float16 hbuf[4][16 * 40];                 // per-wave h transpose, stride 40
  __shared__ float dxbuf[SD * 516];                     // SoA dx, padded plane stride

  const int tid = threadIdx.x;
  const int bx = blockIdx.x, by = blockIdx.y;

  // ---- stage fp32 NHWC -> f16 NHWC LDS tile (zero pad outside) ----
  for (int i = tid; i < (TY + 2) * (TX + 2); i += 256) {
    int ly = i / (TX + 2), lx = i % (TX + 2);
    int gy = by * TY + ly - 1, gx = bx * TX + lx - 1;
    f16x8 v;
#pragma unroll
    for (int j = 0; j < 8; ++j) v[j] = (_Float16)0.0f;
    if ((unsigned)gy < HH && (unsigned)gx < WW) {
      const float* xp = src + (size_t)(gy * WW + gx) * 8;
      f32x4 lo = *(const f32x4*)xp;
      f32x4 hi = *(const f32x4*)(xp + 4);
#pragma unroll
      for (int j = 0; j < 4; ++j) { v[j] = (_Float16)lo[j]; v[4 + j] = (_Float16)hi[j]; }
    }
    *(f16x8*)&tile[i * 8] = v;
  }
  __syncthreads();

  const int lane = tid & 63, w = tid >> 6;
  const int m = lane & 15, q = lane >> 4;

  // B fragments: held in VGPRs for the whole kernel
  f16x8 bf[2][3];
#pragma unroll
  for (int nt = 0; nt < 2; ++nt)
#pragma unroll
    for (int kc = 0; kc < 3; ++kc)
      bf[nt][kc] = *(const f16x8*)(w1f + ((nt * 3 + kc) * 64 + lane) * 8);
  f16x8 w2fr = *(const f16x8*)(w2f + lane * 8);
  const float b1v0 = b1[m], b1v1 = b1[m + 16];
  const float b2v = b2[m & 7];

  // per-lane tap offsets for the 3 K-chunks (taps 9..11 are B=0 rows; clamp A addr)
  int ady[3], adx[3];
#pragma unroll
  for (int kc = 0; kc < 3; ++kc) {
    int t = kc * 4 + q; if (t > 8) t = 0;
    ady[kc] = t / 3; adx[kc] = t - (t / 3) * 3;
  }

  _Float16* hb = &hbuf[w][0];

  for (int r4 = 0; r4 < 4; ++r4) {
    const int y = w * 4 + r4;  // local row 0..15
#pragma unroll
    for (int xh = 0; xh < 2; ++xh) {
      const int x0 = xh * 16;
      f32x4 acc0 = {0.f, 0.f, 0.f, 0.f}, acc1 = {0.f, 0.f, 0.f, 0.f};
#pragma unroll
      for (int kc = 0; kc < 3; ++kc) {
        const f16x8 a = *(const f16x8*)&tile[(((y + ady[kc]) * (TX + 2)) + x0 + m + adx[kc]) * 8];
        acc0 = __builtin_amdgcn_mfma_f32_16x16x32_f16(a, bf[0][kc], acc0, 0, 0, 0);
        acc1 = __builtin_amdgcn_mfma_f32_16x16x32_f16(a, bf[1][kc], acc1, 0, 0, 0);
      }
      // gelu (exact, erf) + transpose h into A-operand layout via per-wave LDS
#pragma unroll
      for (int r = 0; r < 4; ++r) {
        float h0 = acc0[r] + b1v0;
        float h1 = acc1[r] + b1v1;
        h0 = 0.5f * h0 * (1.0f + erff(h0 * 0.70710678118654752440f));
        h1 = 0.5f * h1 * (1.0f + erff(h1 * 0.70710678118654752440f));
        hb[(q * 4 + r) * 40 + m] = (_Float16)h0;        // pixel row q*4+r, channel m
        hb[(q * 4 + r) * 40 + m + 16] = (_Float16)h1;   // channel m+16
      }
      // conv1x1: A2[m][k=q*8+j] = h[pixel m][channel q*8+j]
      const f16x8 a2 = *(const f16x8*)&hb[m * 40 + q * 8];
      f32x4 acc2 = {0.f, 0.f, 0.f, 0.f};
      acc2 = __builtin_amdgcn_mfma_f32_16x16x32_f16(a2, w2fr, acc2, 0, 0, 0);
      if (m < 8) {  // valid output channels
        f32x4 dxv;
#pragma unroll
        for (int r = 0; r < 4; ++r) dxv[r] = (acc2[r] + b2v) * 0.1f;
        // SoA: dxbuf[n][pixel], n = m; pixels q*4..q*4+3 consecutive -> b128
        *(f32x4*)&dxbuf[m * 516 + y * TX + x0 + q * 4] = dxv;
      }
    }
  }
  __syncthreads();

  // ---- update: x_new = x + dx * mask (fp32 path for state) ----
#pragma unroll
  for (int it = 0; it < 2; ++it) {
    const int pl = it * 256 + tid;
    const int y = pl >> 5, x = pl & 31;
    const uint32_t gp = (uint32_t)((by * TY + y) * WW + bx * TX + x);
    float dxv[8];
#pragma unroll
    for (int n = 0; n < 8; ++n) dxv[n] = dxbuf[n * 516 + pl];
    uint32_t r0, r1;
    tf2x32(key0, key1, 0u, gp, r0, r1);
    const float maskf = (((r0 ^ r1) >> 9) > 0x400000u) ? 1.0f : 0.0f;
    const float* xp = src + (size_t)gp * 8;
    f32x4 lo = *(const f32x4*)xp;
    f32x4 hi = *(const f32x4*)(xp + 4);
#pragma unroll
    for (int j = 0; j < 4; ++j) { lo[j] += dxv[j] * maskf; hi[j] += dxv[4 + j] * maskf; }
    float* op = dst + (size_t)gp * 8;
    *(f32x4*)op = lo;
    *(f32x4*)(op + 4) = hi;
  }
}

// ---- projection: out[p] = bp + sum_c x[p][c]*Wp[c] (NHWC) ----
__global__ void proj_kernel(const float* __restrict__ x,
                            const float* __restrict__ Wp,
                            const float* __restrict__ bp,
                            float* __restrict__ out) {
  int p = blockIdx.x * blockDim.x + threadIdx.x;
  if (p >= HH * WW) return;
  const float* xp = x + (size_t)p * 8;
  f32x4 lo = *(const f32x4*)xp;
  f32x4 hi = *(const f32x4*)(xp + 4);
  float acc = bp[0];
#pragma unroll
  for (int c = 0; c < 4; ++c) acc = fmaf(lo[c], Wp[c], acc);
#pragma unroll
  for (int c = 0; c < 4; ++c) acc = fmaf(hi[c], Wp[4 + c], acc);
  out[p] = acc;
}

extern "C" void kernel_launch(void* const* d_in, const int* in_sizes, int n_in,
                              void* d_out, int out_size, void* d_ws, size_t ws_size,
                              hipStream_t stream) {
  (void)in_sizes; (void)n_in; (void)out_size; (void)ws_size;
  const float* seed = (const float*)d_in[0];
  const float* W1   = (const float*)d_in[1];
  const float* b1   = (const float*)d_in[2];
  const float* W2   = (const float*)d_in[3];
  const float* b2   = (const float*)d_in[4];
  const float* Wp   = (const float*)d_in[5];
  const float* bp   = (const float*)d_in[6];
  float* out  = (float*)d_out;
  float* buf0 = (float*)d_ws;
  float* buf1 = buf0 + (size_t)SD * HH * WW;
  _Float16* w1f = (_Float16*)(buf1 + (size_t)SD * HH * WW);
  _Float16* w2f = w1f + 2 * 3 * 64 * 8;

  // 64 subkeys of jax.random.split(jax.random.key(42), 64) (raw pairs, no xor)
  uint32_t ka[64], kb[64];
  for (int i = 0; i < 64; ++i) tf2x32(0u, 42u, 0u, (uint32_t)i, ka[i], kb[i]);

  hipLaunchKernelGGL(prep_kernel, dim3(1), dim3(256), 0, stream, W1, W2, w1f, w2f);
  hipLaunchKernelGGL(init_kernel, dim3((HH * WW) / 256), dim3(256), 0, stream, seed, buf0);

  dim3 grid(WW / TX, HH / TY);
  float* s = buf0; float* d = buf1;
  for (int i = 0; i < 64; ++i) {
    hipLaunchKernelGGL(step_kernel, grid, dim3(256), 0, stream,
                       s, d, w1f, w2f, b1, b2, ka[i], kb[i]);
    float* t = s; s = d; d = t;
  }
  hipLaunchKernelGGL(proj_kernel, dim3((HH * WW) / 256), dim3(256), 0, stream,
                     s, Wp, bp, out);
}